// Round 1
// baseline (19815.088 us; speedup 1.0000x reference)
//
#include <hip/hip_runtime.h>
#include <hip/hip_bf16.h>

#define NN 50000
#define NE 800000
#define LDIM 128
#define NSTEPS 10

typedef __hip_bfloat16 bf16;

// ---------------- degree + center ----------------

__global__ void k_deg(const int* __restrict__ rcv, float* __restrict__ deg) {
    int i = blockIdx.x * 256 + threadIdx.x;
    if (i < NE) atomicAdd(&deg[rcv[i]], 1.0f);
}

__global__ void k_center(const float* __restrict__ pos, float* __restrict__ csum) {
    __shared__ float s[3][256];
    float a = 0.f, b = 0.f, c = 0.f;
    for (int i = blockIdx.x * 256 + threadIdx.x; i < NN; i += gridDim.x * 256) {
        a += pos[3 * i]; b += pos[3 * i + 1]; c += pos[3 * i + 2];
    }
    int t = threadIdx.x;
    s[0][t] = a; s[1][t] = b; s[2][t] = c;
    __syncthreads();
    for (int off = 128; off > 0; off >>= 1) {
        if (t < off) {
            s[0][t] += s[0][t + off];
            s[1][t] += s[1][t + off];
            s[2][t] += s[2][t + off];
        }
        __syncthreads();
    }
    if (t == 0) {
        atomicAdd(&csum[0], s[0][0]);
        atomicAdd(&csum[1], s[1][0]);
        atomicAdd(&csum[2], s[2][0]);
    }
}

// ---------------- node encoder: feat(23) -> 128 -> 128 ----------------

__global__ __launch_bounds__(128) void k_node_enc(
    const float* __restrict__ pos, const float* __restrict__ vel,
    const int* __restrict__ rid, const float* __restrict__ remb,
    const float* __restrict__ deg, const float* __restrict__ csum,
    const float* __restrict__ w1, const float* __restrict__ b1,
    const float* __restrict__ w2, const float* __restrict__ b2,
    float* __restrict__ nl) {
    __shared__ float inl[16][24];
    __shared__ float hid[16][128];
    int j = threadIdx.x;
    int base = blockIdx.x * 16;
    float cx = csum[0] * (1.0f / NN), cy = csum[1] * (1.0f / NN), cz = csum[2] * (1.0f / NN);
    for (int t = j; t < 16 * 23; t += 128) {
        int e = t / 23, k = t - e * 23;
        int n = base + e;
        float v;
        if (k < 3)       v = vel[3 * n + k];
        else if (k < 6)  v = pos[3 * n + k - 3] - (k == 3 ? cx : (k == 4 ? cy : cz));
        else if (k == 6) v = deg[n];
        else             v = remb[rid[n] * 16 + k - 7];
        inl[e][k] = v;
    }
    __syncthreads();
    float acc[16];
#pragma unroll
    for (int e = 0; e < 16; e++) acc[e] = b1[j];
    for (int k = 0; k < 23; k++) {
        float w = w1[k * 128 + j];
#pragma unroll
        for (int e = 0; e < 16; e++) acc[e] = fmaf(inl[e][k], w, acc[e]);
    }
#pragma unroll
    for (int e = 0; e < 16; e++) hid[e][j] = fmaxf(acc[e], 0.f);
    __syncthreads();
#pragma unroll
    for (int e = 0; e < 16; e++) acc[e] = b2[j];
    for (int kc = 0; kc < 16; kc++) {
        float w[8];
#pragma unroll
        for (int t = 0; t < 8; t++) w[t] = w2[(kc * 8 + t) * 128 + j];
#pragma unroll
        for (int e = 0; e < 16; e++) {
            float4 h0 = *(const float4*)&hid[e][kc * 8];
            float4 h1 = *(const float4*)&hid[e][kc * 8 + 4];
            acc[e] = fmaf(h0.x, w[0], acc[e]); acc[e] = fmaf(h0.y, w[1], acc[e]);
            acc[e] = fmaf(h0.z, w[2], acc[e]); acc[e] = fmaf(h0.w, w[3], acc[e]);
            acc[e] = fmaf(h1.x, w[4], acc[e]); acc[e] = fmaf(h1.y, w[5], acc[e]);
            acc[e] = fmaf(h1.z, w[6], acc[e]); acc[e] = fmaf(h1.w, w[7], acc[e]);
        }
    }
#pragma unroll
    for (int e = 0; e < 16; e++) nl[(size_t)(base + e) * 128 + j] = acc[e];
}

// ---------------- edge encoder: feat(9) -> 128 -> 128 ----------------

__global__ __launch_bounds__(128) void k_edge_enc(
    const float* __restrict__ pos, const float* __restrict__ vel,
    const int* __restrict__ rid, const int* __restrict__ snd, const int* __restrict__ rcv,
    const float* __restrict__ w1, const float* __restrict__ b1,
    const float* __restrict__ w2, const float* __restrict__ b2,
    bf16* __restrict__ el) {
    __shared__ float inl[32][9];
    __shared__ float hid[32][128];
    int j = threadIdx.x;
    int base = blockIdx.x * 32;
    if (j < 32) {
        int e = base + j;
        int s = snd[e], r = rcv[e];
        float px = pos[3 * s] - pos[3 * r], py = pos[3 * s + 1] - pos[3 * r + 1], pz = pos[3 * s + 2] - pos[3 * r + 2];
        float vx = vel[3 * s] - vel[3 * r], vy = vel[3 * s + 1] - vel[3 * r + 1], vz = vel[3 * s + 2] - vel[3 * r + 2];
        float sq = px * px + py * py + pz * pz;
        inl[j][0] = px; inl[j][1] = py; inl[j][2] = pz;
        inl[j][3] = vx; inl[j][4] = vy; inl[j][5] = vz;
        inl[j][6] = sqrtf(sq); inl[j][7] = sq;
        inl[j][8] = (rid[s] == rid[r]) ? 1.f : 0.f;
    }
    __syncthreads();
    float acc[32];
#pragma unroll
    for (int e = 0; e < 32; e++) acc[e] = b1[j];
    for (int k = 0; k < 9; k++) {
        float w = w1[k * 128 + j];
#pragma unroll
        for (int e = 0; e < 32; e++) acc[e] = fmaf(inl[e][k], w, acc[e]);
    }
#pragma unroll
    for (int e = 0; e < 32; e++) hid[e][j] = fmaxf(acc[e], 0.f);
    __syncthreads();
#pragma unroll
    for (int e = 0; e < 32; e++) acc[e] = b2[j];
    for (int kc = 0; kc < 16; kc++) {
        float w[8];
#pragma unroll
        for (int t = 0; t < 8; t++) w[t] = w2[(kc * 8 + t) * 128 + j];
        for (int e = 0; e < 32; e++) {
            float4 h0 = *(const float4*)&hid[e][kc * 8];
            float4 h1 = *(const float4*)&hid[e][kc * 8 + 4];
            acc[e] = fmaf(h0.x, w[0], acc[e]); acc[e] = fmaf(h0.y, w[1], acc[e]);
            acc[e] = fmaf(h0.z, w[2], acc[e]); acc[e] = fmaf(h0.w, w[3], acc[e]);
            acc[e] = fmaf(h1.x, w[4], acc[e]); acc[e] = fmaf(h1.y, w[5], acc[e]);
            acc[e] = fmaf(h1.z, w[6], acc[e]); acc[e] = fmaf(h1.w, w[7], acc[e]);
        }
    }
#pragma unroll
    for (int e = 0; e < 32; e++) el[(size_t)(base + e) * 128 + j] = __float2bfloat16(acc[e]);
}

// ---------------- edge processor step: [el|nl_s|nl_r](384) -> 128 -> 128, residual + scatter ----------------
// 256 threads = 4 groups of 64 lanes; each group handles 8 edges, each thread 2 channels (c, c+64).
// LDS: inl[32][384]; hidden layer reuses inl[e][256:384] (nl_r segment, dead after layer 1).

__global__ __launch_bounds__(256) void k_edge_step(
    bf16* __restrict__ el, const float* __restrict__ nl,
    const int* __restrict__ snd, const int* __restrict__ rcv,
    const float* __restrict__ w1, const float* __restrict__ b1,
    const float* __restrict__ w2, const float* __restrict__ b2,
    float* __restrict__ agg) {
    __shared__ float inl[32][384];
    __shared__ int sh_r[32];
    int tid = threadIdx.x;
    int base = blockIdx.x * 32;
    {
        int j = tid & 127, half = tid >> 7;
        for (int e = half * 16; e < half * 16 + 16; e++) {
            int ge = base + e;
            int s = snd[ge], r = rcv[ge];
            if (j == 0) sh_r[e] = r;
            inl[e][j]       = __bfloat162float(el[(size_t)ge * 128 + j]);
            inl[e][128 + j] = nl[(size_t)s * 128 + j];
            inl[e][256 + j] = nl[(size_t)r * 128 + j];
        }
    }
    __syncthreads();
    int c = tid & 63, g = tid >> 6, e0 = g * 8;
    float a0[8], a1[8];
#pragma unroll
    for (int e = 0; e < 8; e++) { a0[e] = b1[c]; a1[e] = b1[c + 64]; }
    for (int kc = 0; kc < 48; kc++) {
        float w0[8], w1r[8];
#pragma unroll
        for (int t = 0; t < 8; t++) {
            w0[t]  = w1[(kc * 8 + t) * 128 + c];
            w1r[t] = w1[(kc * 8 + t) * 128 + c + 64];
        }
#pragma unroll
        for (int e = 0; e < 8; e++) {
            const float4 i0 = *(const float4*)&inl[e0 + e][kc * 8];
            const float4 i1 = *(const float4*)&inl[e0 + e][kc * 8 + 4];
            a0[e] = fmaf(i0.x, w0[0], a0[e]); a0[e] = fmaf(i0.y, w0[1], a0[e]);
            a0[e] = fmaf(i0.z, w0[2], a0[e]); a0[e] = fmaf(i0.w, w0[3], a0[e]);
            a0[e] = fmaf(i1.x, w0[4], a0[e]); a0[e] = fmaf(i1.y, w0[5], a0[e]);
            a0[e] = fmaf(i1.z, w0[6], a0[e]); a0[e] = fmaf(i1.w, w0[7], a0[e]);
            a1[e] = fmaf(i0.x, w1r[0], a1[e]); a1[e] = fmaf(i0.y, w1r[1], a1[e]);
            a1[e] = fmaf(i0.z, w1r[2], a1[e]); a1[e] = fmaf(i0.w, w1r[3], a1[e]);
            a1[e] = fmaf(i1.x, w1r[4], a1[e]); a1[e] = fmaf(i1.y, w1r[5], a1[e]);
            a1[e] = fmaf(i1.z, w1r[6], a1[e]); a1[e] = fmaf(i1.w, w1r[7], a1[e]);
        }
    }
    __syncthreads();  // everyone done reading inl[*][256:384] for layer 1
#pragma unroll
    for (int e = 0; e < 8; e++) {
        inl[e0 + e][256 + c]      = fmaxf(a0[e], 0.f);
        inl[e0 + e][256 + c + 64] = fmaxf(a1[e], 0.f);
    }
    __syncthreads();
#pragma unroll
    for (int e = 0; e < 8; e++) { a0[e] = b2[c]; a1[e] = b2[c + 64]; }
    for (int kc = 0; kc < 16; kc++) {
        float w0[8], w1r[8];
#pragma unroll
        for (int t = 0; t < 8; t++) {
            w0[t]  = w2[(kc * 8 + t) * 128 + c];
            w1r[t] = w2[(kc * 8 + t) * 128 + c + 64];
        }
#pragma unroll
        for (int e = 0; e < 8; e++) {
            const float4 i0 = *(const float4*)&inl[e0 + e][256 + kc * 8];
            const float4 i1 = *(const float4*)&inl[e0 + e][256 + kc * 8 + 4];
            a0[e] = fmaf(i0.x, w0[0], a0[e]); a0[e] = fmaf(i0.y, w0[1], a0[e]);
            a0[e] = fmaf(i0.z, w0[2], a0[e]); a0[e] = fmaf(i0.w, w0[3], a0[e]);
            a0[e] = fmaf(i1.x, w0[4], a0[e]); a0[e] = fmaf(i1.y, w0[5], a0[e]);
            a0[e] = fmaf(i1.z, w0[6], a0[e]); a0[e] = fmaf(i1.w, w0[7], a0[e]);
            a1[e] = fmaf(i0.x, w1r[0], a1[e]); a1[e] = fmaf(i0.y, w1r[1], a1[e]);
            a1[e] = fmaf(i0.z, w1r[2], a1[e]); a1[e] = fmaf(i0.w, w1r[3], a1[e]);
            a1[e] = fmaf(i1.x, w1r[4], a1[e]); a1[e] = fmaf(i1.y, w1r[5], a1[e]);
            a1[e] = fmaf(i1.z, w1r[6], a1[e]); a1[e] = fmaf(i1.w, w1r[7], a1[e]);
        }
    }
#pragma unroll
    for (int e = 0; e < 8; e++) {
        int ee = e0 + e;
        size_t ge = (size_t)(base + ee);
        float v0 = inl[ee][c]      + a0[e];   // residual: old el still intact in inl[:,0:128]
        float v1 = inl[ee][c + 64] + a1[e];
        el[ge * 128 + c]      = __float2bfloat16(v0);
        el[ge * 128 + c + 64] = __float2bfloat16(v1);
        int r = sh_r[ee];
        atomicAdd(&agg[(size_t)r * 128 + c], v0);
        atomicAdd(&agg[(size_t)r * 128 + c + 64], v1);
    }
}

// ---------------- node processor step: [nl|agg](256) -> 128 -> 128, residual ----------------

__global__ __launch_bounds__(128) void k_node_step(
    float* __restrict__ nl, const float* __restrict__ agg,
    const float* __restrict__ w1, const float* __restrict__ b1,
    const float* __restrict__ w2, const float* __restrict__ b2) {
    __shared__ float inl[16][256];
    int j = threadIdx.x;
    int base = blockIdx.x * 16;
    for (int e = 0; e < 16; e++) {
        inl[e][j]       = nl[(size_t)(base + e) * 128 + j];
        inl[e][128 + j] = agg[(size_t)(base + e) * 128 + j];
    }
    __syncthreads();
    float acc[16];
#pragma unroll
    for (int e = 0; e < 16; e++) acc[e] = b1[j];
    for (int kc = 0; kc < 32; kc++) {
        float w[8];
#pragma unroll
        for (int t = 0; t < 8; t++) w[t] = w1[(kc * 8 + t) * 128 + j];
#pragma unroll
        for (int e = 0; e < 16; e++) {
            float4 h0 = *(const float4*)&inl[e][kc * 8];
            float4 h1 = *(const float4*)&inl[e][kc * 8 + 4];
            acc[e] = fmaf(h0.x, w[0], acc[e]); acc[e] = fmaf(h0.y, w[1], acc[e]);
            acc[e] = fmaf(h0.z, w[2], acc[e]); acc[e] = fmaf(h0.w, w[3], acc[e]);
            acc[e] = fmaf(h1.x, w[4], acc[e]); acc[e] = fmaf(h1.y, w[5], acc[e]);
            acc[e] = fmaf(h1.z, w[6], acc[e]); acc[e] = fmaf(h1.w, w[7], acc[e]);
        }
    }
    __syncthreads();  // done reading inl[:,128:256] (agg segment)
#pragma unroll
    for (int e = 0; e < 16; e++) inl[e][128 + j] = fmaxf(acc[e], 0.f);
    __syncthreads();
#pragma unroll
    for (int e = 0; e < 16; e++) acc[e] = b2[j];
    for (int kc = 0; kc < 16; kc++) {
        float w[8];
#pragma unroll
        for (int t = 0; t < 8; t++) w[t] = w2[(kc * 8 + t) * 128 + j];
#pragma unroll
        for (int e = 0; e < 16; e++) {
            float4 h0 = *(const float4*)&inl[e][128 + kc * 8];
            float4 h1 = *(const float4*)&inl[e][128 + kc * 8 + 4];
            acc[e] = fmaf(h0.x, w[0], acc[e]); acc[e] = fmaf(h0.y, w[1], acc[e]);
            acc[e] = fmaf(h0.z, w[2], acc[e]); acc[e] = fmaf(h0.w, w[3], acc[e]);
            acc[e] = fmaf(h1.x, w[4], acc[e]); acc[e] = fmaf(h1.y, w[5], acc[e]);
            acc[e] = fmaf(h1.z, w[6], acc[e]); acc[e] = fmaf(h1.w, w[7], acc[e]);
        }
    }
#pragma unroll
    for (int e = 0; e < 16; e++)
        nl[(size_t)(base + e) * 128 + j] = inl[e][j] + acc[e];
}

// ---------------- decoder: 128 -> 128 -> 3 ----------------

__global__ __launch_bounds__(128) void k_decode(
    const float* __restrict__ nl,
    const float* __restrict__ w1, const float* __restrict__ b1,
    const float* __restrict__ w2, const float* __restrict__ b2,
    float* __restrict__ out) {
    __shared__ float inl[16][128];
    __shared__ float hid[16][128];
    int j = threadIdx.x;
    int base = blockIdx.x * 16;
    for (int e = 0; e < 16; e++) inl[e][j] = nl[(size_t)(base + e) * 128 + j];
    __syncthreads();
    float acc[16];
#pragma unroll
    for (int e = 0; e < 16; e++) acc[e] = b1[j];
    for (int kc = 0; kc < 16; kc++) {
        float w[8];
#pragma unroll
        for (int t = 0; t < 8; t++) w[t] = w1[(kc * 8 + t) * 128 + j];
#pragma unroll
        for (int e = 0; e < 16; e++) {
            float4 h0 = *(const float4*)&inl[e][kc * 8];
            float4 h1 = *(const float4*)&inl[e][kc * 8 + 4];
            acc[e] = fmaf(h0.x, w[0], acc[e]); acc[e] = fmaf(h0.y, w[1], acc[e]);
            acc[e] = fmaf(h0.z, w[2], acc[e]); acc[e] = fmaf(h0.w, w[3], acc[e]);
            acc[e] = fmaf(h1.x, w[4], acc[e]); acc[e] = fmaf(h1.y, w[5], acc[e]);
            acc[e] = fmaf(h1.z, w[6], acc[e]); acc[e] = fmaf(h1.w, w[7], acc[e]);
        }
    }
#pragma unroll
    for (int e = 0; e < 16; e++) hid[e][j] = fmaxf(acc[e], 0.f);
    __syncthreads();
    if (j < 48) {
        int e = j / 3, ch = j - 3 * (j / 3);
        float s = b2[ch];
        for (int k = 0; k < 128; k++) s = fmaf(hid[e][k], w2[k * 3 + ch], s);
        out[(size_t)(base + e) * 3 + ch] = s;
    }
}

// ---------------- launch ----------------

extern "C" void kernel_launch(void* const* d_in, const int* in_sizes, int n_in,
                              void* d_out, int out_size, void* d_ws, size_t ws_size,
                              hipStream_t stream) {
    (void)in_sizes; (void)n_in; (void)out_size; (void)ws_size;
    const float* pos   = (const float*)d_in[0];
    const float* vel   = (const float*)d_in[1];
    const int*   rid   = (const int*)d_in[2];
    const int*   snd   = (const int*)d_in[3];
    const int*   rcv   = (const int*)d_in[4];
    const float* remb  = (const float*)d_in[5];
    const float* ne_w1 = (const float*)d_in[6];
    const float* ne_b1 = (const float*)d_in[7];
    const float* ne_w2 = (const float*)d_in[8];
    const float* ne_b2 = (const float*)d_in[9];
    const float* ee_w1 = (const float*)d_in[10];
    const float* ee_b1 = (const float*)d_in[11];
    const float* ee_w2 = (const float*)d_in[12];
    const float* ee_b2 = (const float*)d_in[13];
    const float* pe_w1 = (const float*)d_in[14];
    const float* pe_b1 = (const float*)d_in[15];
    const float* pe_w2 = (const float*)d_in[16];
    const float* pe_b2 = (const float*)d_in[17];
    const float* pn_w1 = (const float*)d_in[18];
    const float* pn_b1 = (const float*)d_in[19];
    const float* pn_w2 = (const float*)d_in[20];
    const float* pn_b2 = (const float*)d_in[21];
    const float* de_w1 = (const float*)d_in[22];
    const float* de_b1 = (const float*)d_in[23];
    const float* de_w2 = (const float*)d_in[24];
    const float* de_b2 = (const float*)d_in[25];
    float* out = (float*)d_out;

    // workspace carve (~256.2 MB total)
    char* p = (char*)d_ws;
    bf16*  el   = (bf16*)p;  p += (size_t)NE * LDIM * sizeof(bf16);   // 204.8 MB
    float* nl   = (float*)p; p += (size_t)NN * LDIM * sizeof(float);  // 25.6 MB
    float* agg  = (float*)p; p += (size_t)NN * LDIM * sizeof(float);  // 25.6 MB
    float* deg  = (float*)p; p += (size_t)NN * sizeof(float);         // 0.2 MB
    float* csum = (float*)p; p += 4 * sizeof(float);

    hipMemsetAsync(deg, 0, ((size_t)NN + 4) * sizeof(float), stream);  // deg + csum
    k_deg<<<(NE + 255) / 256, 256, 0, stream>>>(rcv, deg);
    k_center<<<64, 256, 0, stream>>>(pos, csum);
    k_node_enc<<<NN / 16, 128, 0, stream>>>(pos, vel, rid, remb, deg, csum,
                                            ne_w1, ne_b1, ne_w2, ne_b2, nl);
    k_edge_enc<<<NE / 32, 128, 0, stream>>>(pos, vel, rid, snd, rcv,
                                            ee_w1, ee_b1, ee_w2, ee_b2, el);
    for (int i = 0; i < NSTEPS; i++) {
        hipMemsetAsync(agg, 0, (size_t)NN * LDIM * sizeof(float), stream);
        k_edge_step<<<NE / 32, 256, 0, stream>>>(el, nl, snd, rcv,
            pe_w1 + (size_t)i * 384 * 128, pe_b1 + i * 128,
            pe_w2 + (size_t)i * 128 * 128, pe_b2 + i * 128, agg);
        k_node_step<<<NN / 16, 128, 0, stream>>>(nl, agg,
            pn_w1 + (size_t)i * 256 * 128, pn_b1 + i * 128,
            pn_w2 + (size_t)i * 128 * 128, pn_b2 + i * 128);
    }
    k_decode<<<NN / 16, 128, 0, stream>>>(nl, de_w1, de_b1, de_w2, de_b2, out);
}

// Round 2
// 4152.789 us; speedup vs baseline: 4.7715x; 4.7715x over previous
//
#include <hip/hip_runtime.h>
#include <hip/hip_bf16.h>

#define NN 50000
#define NE 800000
#define LDIM 128
#define NSTEPS 10

typedef __hip_bfloat16 bf16;
typedef __bf16 bf8v __attribute__((ext_vector_type(8)));
typedef float f4v __attribute__((ext_vector_type(4)));
typedef unsigned short u16x8 __attribute__((ext_vector_type(8)));

__device__ inline float bflo(unsigned int u) {  // low 16 bits are a bf16
    union { unsigned int i; float f; } x; x.i = u << 16; return x.f;
}
__device__ inline float bfhi(unsigned int u) {  // high 16 bits are a bf16
    union { unsigned int i; float f; } x; x.i = u & 0xffff0000u; return x.f;
}
__device__ inline unsigned short f2bf(float f) {
    __hip_bfloat16 h = __float2bfloat16(f);
    unsigned short u; __builtin_memcpy(&u, &h, 2); return u;
}

// ---------------- CSR build: histogram, scan, scatter ----------------

__global__ void k_hist(const int* __restrict__ rcv, int* __restrict__ cnt) {
    int i = blockIdx.x * 256 + threadIdx.x;
    if (i < NE) atomicAdd(&cnt[rcv[i]], 1);
}

__global__ __launch_bounds__(1024) void k_scan(
    const int* __restrict__ cnt, int* __restrict__ row_start,
    int* __restrict__ cur, float* __restrict__ degf) {
    __shared__ int part[1024];
    const int t = threadIdx.x;
    const int CH = (NN + 1023) / 1024;  // 49
    int b0 = t * CH, b1 = b0 + CH; if (b1 > NN) b1 = NN; if (b0 > NN) b0 = NN;
    int s = 0;
    for (int i = b0; i < b1; i++) s += cnt[i];
    part[t] = s;
    __syncthreads();
    for (int off = 1; off < 1024; off <<= 1) {
        int v = (t >= off) ? part[t - off] : 0;
        __syncthreads();
        part[t] += v;
        __syncthreads();
    }
    int run = part[t] - s;  // exclusive prefix
    for (int i = b0; i < b1; i++) {
        row_start[i] = run; cur[i] = run; degf[i] = (float)cnt[i];
        run += cnt[i];
    }
    if (t == 1023) row_start[NN] = part[1023];
}

__global__ void k_scatter(const int* __restrict__ rcv, int* __restrict__ cur,
                          int* __restrict__ eidx) {
    int i = blockIdx.x * 256 + threadIdx.x;
    if (i < NE) {
        int p = atomicAdd(&cur[rcv[i]], 1);
        eidx[p] = i;
    }
}

__global__ void k_center(const float* __restrict__ pos, float* __restrict__ csum) {
    __shared__ float s[3][256];
    float a = 0.f, b = 0.f, c = 0.f;
    for (int i = blockIdx.x * 256 + threadIdx.x; i < NN; i += gridDim.x * 256) {
        a += pos[3 * i]; b += pos[3 * i + 1]; c += pos[3 * i + 2];
    }
    int t = threadIdx.x;
    s[0][t] = a; s[1][t] = b; s[2][t] = c;
    __syncthreads();
    for (int off = 128; off > 0; off >>= 1) {
        if (t < off) {
            s[0][t] += s[0][t + off];
            s[1][t] += s[1][t + off];
            s[2][t] += s[2][t + off];
        }
        __syncthreads();
    }
    if (t == 0) {
        atomicAdd(&csum[0], s[0][0]);
        atomicAdd(&csum[1], s[1][0]);
        atomicAdd(&csum[2], s[2][0]);
    }
}

// ---------------- weight prep: fp32 [K][128] -> bf16 MFMA B-fragment order ----------------
// frag layout: wf[((s*KT*8 + kt*8 + nt)*64 + lane)*8 + j] = bf16(w[s][kt*32+quad*8+j][nt*16+col])

__global__ void k_prep_w(const float* __restrict__ w, unsigned short* __restrict__ wf, int KT) {
    int b = blockIdx.x;
    int s = b / (KT * 8), rem = b % (KT * 8);
    int kt = rem / 8, nt = rem % 8;
    int lane = threadIdx.x, col = lane & 15, quad = lane >> 4;
    const float* W = w + (size_t)s * (KT * 32) * 128;
    u16x8 o;
#pragma unroll
    for (int jj = 0; jj < 8; jj++)
        o[jj] = f2bf(W[(size_t)(kt * 32 + quad * 8 + jj) * 128 + nt * 16 + col]);
    *(u16x8*)(wf + (((size_t)b) * 64 + lane) * 8) = o;
}

// ---------------- node encoder: feat(23) -> 128 -> 128 ----------------

__global__ __launch_bounds__(128) void k_node_enc(
    const float* __restrict__ pos, const float* __restrict__ vel,
    const int* __restrict__ rid, const float* __restrict__ remb,
    const float* __restrict__ degf, const float* __restrict__ csum,
    const float* __restrict__ w1, const float* __restrict__ b1,
    const float* __restrict__ w2, const float* __restrict__ b2,
    float* __restrict__ nl, unsigned short* __restrict__ nlb) {
    __shared__ float inl[16][24];
    __shared__ float hid[16][128];
    int j = threadIdx.x;
    int base = blockIdx.x * 16;
    float cx = csum[0] * (1.0f / NN), cy = csum[1] * (1.0f / NN), cz = csum[2] * (1.0f / NN);
    for (int t = j; t < 16 * 23; t += 128) {
        int e = t / 23, k = t - e * 23;
        int n = base + e;
        float v;
        if (k < 3)       v = vel[3 * n + k];
        else if (k < 6)  v = pos[3 * n + k - 3] - (k == 3 ? cx : (k == 4 ? cy : cz));
        else if (k == 6) v = degf[n];
        else             v = remb[rid[n] * 16 + k - 7];
        inl[e][k] = v;
    }
    __syncthreads();
    float acc[16];
#pragma unroll
    for (int e = 0; e < 16; e++) acc[e] = b1[j];
    for (int k = 0; k < 23; k++) {
        float w = w1[k * 128 + j];
#pragma unroll
        for (int e = 0; e < 16; e++) acc[e] = fmaf(inl[e][k], w, acc[e]);
    }
#pragma unroll
    for (int e = 0; e < 16; e++) hid[e][j] = fmaxf(acc[e], 0.f);
    __syncthreads();
#pragma unroll
    for (int e = 0; e < 16; e++) acc[e] = b2[j];
    for (int kc = 0; kc < 16; kc++) {
        float w[8];
#pragma unroll
        for (int t = 0; t < 8; t++) w[t] = w2[(kc * 8 + t) * 128 + j];
#pragma unroll
        for (int e = 0; e < 16; e++) {
            float4 h0 = *(const float4*)&hid[e][kc * 8];
            float4 h1 = *(const float4*)&hid[e][kc * 8 + 4];
            acc[e] = fmaf(h0.x, w[0], acc[e]); acc[e] = fmaf(h0.y, w[1], acc[e]);
            acc[e] = fmaf(h0.z, w[2], acc[e]); acc[e] = fmaf(h0.w, w[3], acc[e]);
            acc[e] = fmaf(h1.x, w[4], acc[e]); acc[e] = fmaf(h1.y, w[5], acc[e]);
            acc[e] = fmaf(h1.z, w[6], acc[e]); acc[e] = fmaf(h1.w, w[7], acc[e]);
        }
    }
#pragma unroll
    for (int e = 0; e < 16; e++) {
        float v = acc[e];
        nl[(size_t)(base + e) * 128 + j] = v;
        nlb[(size_t)(base + e) * 128 + j] = f2bf(v);
    }
}

// ---------------- edge encoder: feat(9) -> 128 -> 128 ----------------

__global__ __launch_bounds__(128) void k_edge_enc(
    const float* __restrict__ pos, const float* __restrict__ vel,
    const int* __restrict__ rid, const int* __restrict__ snd, const int* __restrict__ rcv,
    const float* __restrict__ w1, const float* __restrict__ b1,
    const float* __restrict__ w2, const float* __restrict__ b2,
    bf16* __restrict__ el) {
    __shared__ float inl[32][9];
    __shared__ float hid[32][128];
    int j = threadIdx.x;
    int base = blockIdx.x * 32;
    if (j < 32) {
        int e = base + j;
        int s = snd[e], r = rcv[e];
        float px = pos[3 * s] - pos[3 * r], py = pos[3 * s + 1] - pos[3 * r + 1], pz = pos[3 * s + 2] - pos[3 * r + 2];
        float vx = vel[3 * s] - vel[3 * r], vy = vel[3 * s + 1] - vel[3 * r + 1], vz = vel[3 * s + 2] - vel[3 * r + 2];
        float sq = px * px + py * py + pz * pz;
        inl[j][0] = px; inl[j][1] = py; inl[j][2] = pz;
        inl[j][3] = vx; inl[j][4] = vy; inl[j][5] = vz;
        inl[j][6] = sqrtf(sq); inl[j][7] = sq;
        inl[j][8] = (rid[s] == rid[r]) ? 1.f : 0.f;
    }
    __syncthreads();
    float acc[32];
#pragma unroll
    for (int e = 0; e < 32; e++) acc[e] = b1[j];
    for (int k = 0; k < 9; k++) {
        float w = w1[k * 128 + j];
#pragma unroll
        for (int e = 0; e < 32; e++) acc[e] = fmaf(inl[e][k], w, acc[e]);
    }
#pragma unroll
    for (int e = 0; e < 32; e++) hid[e][j] = fmaxf(acc[e], 0.f);
    __syncthreads();
#pragma unroll
    for (int e = 0; e < 32; e++) acc[e] = b2[j];
    for (int kc = 0; kc < 16; kc++) {
        float w[8];
#pragma unroll
        for (int t = 0; t < 8; t++) w[t] = w2[(kc * 8 + t) * 128 + j];
#pragma unroll
        for (int e = 0; e < 32; e++) {   // pragma added: was scratch-spilling acc[]
            float4 h0 = *(const float4*)&hid[e][kc * 8];
            float4 h1 = *(const float4*)&hid[e][kc * 8 + 4];
            acc[e] = fmaf(h0.x, w[0], acc[e]); acc[e] = fmaf(h0.y, w[1], acc[e]);
            acc[e] = fmaf(h0.z, w[2], acc[e]); acc[e] = fmaf(h0.w, w[3], acc[e]);
            acc[e] = fmaf(h1.x, w[4], acc[e]); acc[e] = fmaf(h1.y, w[5], acc[e]);
            acc[e] = fmaf(h1.z, w[6], acc[e]); acc[e] = fmaf(h1.w, w[7], acc[e]);
        }
    }
#pragma unroll
    for (int e = 0; e < 32; e++) el[(size_t)(base + e) * 128 + j] = __float2bfloat16(acc[e]);
}

// ---------------- MFMA edge processor step ----------------
// 256 thr = 4 waves. Per block: 4 tiles of 32 edges (128 edges). Per tile:
// A=[el|nl_s|nl_r] (32x384 bf16, LDS stride 392), L1 -> hid (32x128 bf16, stride 136),
// L2 -> +bias+residual -> out (reuses hid region) -> staged uint4 store to el.
// Wave w owns N-cols [32w,32w+32): tiles (mt in {0,1}) x (nt in {2w,2w+1}).
// Weights held in registers in B-frag order (B[n=lane&15][k=quad*8+j]).

__global__ __launch_bounds__(256) void k_edge_step(
    unsigned short* __restrict__ el, const unsigned short* __restrict__ nlb,
    const int* __restrict__ snd, const int* __restrict__ rcv,
    const unsigned short* __restrict__ w1f, const float* __restrict__ b1,
    const unsigned short* __restrict__ w2f, const float* __restrict__ b2) {
    __shared__ __align__(16) unsigned short inl_s[32 * 392];
    __shared__ __align__(16) unsigned short hid_s[32 * 136];
    __shared__ int s_idx[64];
    const int tid = threadIdx.x;
    const int wave = tid >> 6, lane = tid & 63;
    const int col = lane & 15, quad = lane >> 4;

    bf8v W1[12][2], W2[4][2];
#pragma unroll
    for (int kt = 0; kt < 12; kt++)
#pragma unroll
        for (int t = 0; t < 2; t++)
            W1[kt][t] = *(const bf8v*)(w1f + ((size_t)(kt * 8 + 2 * wave + t) * 64 + lane) * 8);
#pragma unroll
    for (int kt = 0; kt < 4; kt++)
#pragma unroll
        for (int t = 0; t < 2; t++)
            W2[kt][t] = *(const bf8v*)(w2f + ((size_t)(kt * 8 + 2 * wave + t) * 64 + lane) * 8);
    float bias1[2], bias2[2];
#pragma unroll
    for (int t = 0; t < 2; t++) {
        bias1[t] = b1[(2 * wave + t) * 16 + col];
        bias2[t] = b2[(2 * wave + t) * 16 + col];
    }

    for (int it = 0; it < 4; it++) {
        const int base = blockIdx.x * 128 + it * 32;
        if (tid < 64) s_idx[tid] = (tid < 32) ? snd[base + tid] : rcv[base + tid - 32];
        __syncthreads();  // A: s_idx ready; prev-iter inl/hid reads done
#pragma unroll
        for (int p = 0; p < 2; p++) {
            int s = p * 256 + tid, e = s >> 4, c16 = s & 15;
            *(uint4*)(inl_s + e * 392 + c16 * 8) =
                *(const uint4*)(el + (size_t)(base + e) * 128 + c16 * 8);
            *(uint4*)(inl_s + e * 392 + 128 + c16 * 8) =
                *(const uint4*)(nlb + (size_t)s_idx[e] * 128 + c16 * 8);
            *(uint4*)(inl_s + e * 392 + 256 + c16 * 8) =
                *(const uint4*)(nlb + (size_t)s_idx[32 + e] * 128 + c16 * 8);
        }
        __syncthreads();  // B: staging done

        f4v acc[2][2];
#pragma unroll
        for (int mt = 0; mt < 2; mt++)
#pragma unroll
            for (int t = 0; t < 2; t++) acc[mt][t] = (f4v){0.f, 0.f, 0.f, 0.f};
#pragma unroll
        for (int kt = 0; kt < 12; kt++) {
            bf8v a0 = *(const bf8v*)(inl_s + col * 392 + kt * 32 + quad * 8);
            bf8v a1 = *(const bf8v*)(inl_s + (16 + col) * 392 + kt * 32 + quad * 8);
            acc[0][0] = __builtin_amdgcn_mfma_f32_16x16x32_bf16(a0, W1[kt][0], acc[0][0], 0, 0, 0);
            acc[0][1] = __builtin_amdgcn_mfma_f32_16x16x32_bf16(a0, W1[kt][1], acc[0][1], 0, 0, 0);
            acc[1][0] = __builtin_amdgcn_mfma_f32_16x16x32_bf16(a1, W1[kt][0], acc[1][0], 0, 0, 0);
            acc[1][1] = __builtin_amdgcn_mfma_f32_16x16x32_bf16(a1, W1[kt][1], acc[1][1], 0, 0, 0);
        }
#pragma unroll
        for (int mt = 0; mt < 2; mt++)
#pragma unroll
            for (int t = 0; t < 2; t++) {
                const int nc = (2 * wave + t) * 16 + col;
#pragma unroll
                for (int r = 0; r < 4; r++) {
                    float v = fmaxf(acc[mt][t][r] + bias1[t], 0.f);
                    hid_s[(mt * 16 + quad * 4 + r) * 136 + nc] = f2bf(v);
                }
            }
        __syncthreads();  // C: hid ready

#pragma unroll
        for (int mt = 0; mt < 2; mt++)
#pragma unroll
            for (int t = 0; t < 2; t++) acc[mt][t] = (f4v){0.f, 0.f, 0.f, 0.f};
#pragma unroll
        for (int kt = 0; kt < 4; kt++) {
            bf8v a0 = *(const bf8v*)(hid_s + col * 136 + kt * 32 + quad * 8);
            bf8v a1 = *(const bf8v*)(hid_s + (16 + col) * 136 + kt * 32 + quad * 8);
            acc[0][0] = __builtin_amdgcn_mfma_f32_16x16x32_bf16(a0, W2[kt][0], acc[0][0], 0, 0, 0);
            acc[0][1] = __builtin_amdgcn_mfma_f32_16x16x32_bf16(a0, W2[kt][1], acc[0][1], 0, 0, 0);
            acc[1][0] = __builtin_amdgcn_mfma_f32_16x16x32_bf16(a1, W2[kt][0], acc[1][0], 0, 0, 0);
            acc[1][1] = __builtin_amdgcn_mfma_f32_16x16x32_bf16(a1, W2[kt][1], acc[1][1], 0, 0, 0);
        }
        __syncthreads();  // D: all waves done reading hid; safe to overwrite with out
#pragma unroll
        for (int mt = 0; mt < 2; mt++)
#pragma unroll
            for (int t = 0; t < 2; t++) {
                const int nc = (2 * wave + t) * 16 + col;
#pragma unroll
                for (int r = 0; r < 4; r++) {
                    const int row = mt * 16 + quad * 4 + r;
                    float v = acc[mt][t][r] + bias2[t] + bflo((unsigned int)inl_s[row * 392 + nc]);
                    hid_s[row * 136 + nc] = f2bf(v);
                }
            }
        __syncthreads();  // E: out staged in LDS
#pragma unroll
        for (int p = 0; p < 2; p++) {
            int s = p * 256 + tid, e = s >> 4, c16 = s & 15;
            *(uint4*)(el + (size_t)(base + e) * 128 + c16 * 8) =
                *(const uint4*)(hid_s + e * 136 + c16 * 8);
        }
    }
}

// ---------------- node step: CSR gather-sum + [nl|agg](256) -> 128 -> 128, residual ----------------

__global__ __launch_bounds__(128) void k_node_step(
    float* __restrict__ nl, unsigned short* __restrict__ nlb,
    const unsigned short* __restrict__ el,
    const int* __restrict__ eidx, const int* __restrict__ row_start,
    const float* __restrict__ w1, const float* __restrict__ b1,
    const float* __restrict__ w2, const float* __restrict__ b2) {
    __shared__ float inl[16][256];
    int j = threadIdx.x;
    int base = blockIdx.x * 16;
    for (int e = 0; e < 16; e++) inl[e][j] = nl[(size_t)(base + e) * 128 + j];
    // CSR gather: wave wv handles nodes wv*8..wv*8+7; 4 lane-groups x 4 edges in flight
    int wv = j >> 6, lane = j & 63, sub = lane >> 4, c16 = lane & 15;
    for (int i = 0; i < 8; i++) {
        int n = base + wv * 8 + i;
        int st = row_start[n], en = row_start[n + 1];
        float s[8];
#pragma unroll
        for (int k = 0; k < 8; k++) s[k] = 0.f;
        for (int q = st + sub; q < en; q += 4) {
            uint4 v = *(const uint4*)(el + (size_t)eidx[q] * 128 + c16 * 8);
            s[0] += bflo(v.x); s[1] += bfhi(v.x);
            s[2] += bflo(v.y); s[3] += bfhi(v.y);
            s[4] += bflo(v.z); s[5] += bfhi(v.z);
            s[6] += bflo(v.w); s[7] += bfhi(v.w);
        }
#pragma unroll
        for (int k = 0; k < 8; k++) {
            s[k] += __shfl_xor(s[k], 16);
            s[k] += __shfl_xor(s[k], 32);
        }
        if (sub == 0) {
#pragma unroll
            for (int k = 0; k < 8; k++) inl[wv * 8 + i][128 + c16 * 8 + k] = s[k];
        }
    }
    __syncthreads();
    float acc[16];
#pragma unroll
    for (int e = 0; e < 16; e++) acc[e] = b1[j];
    for (int kc = 0; kc < 32; kc++) {
        float w[8];
#pragma unroll
        for (int t = 0; t < 8; t++) w[t] = w1[(kc * 8 + t) * 128 + j];
#pragma unroll
        for (int e = 0; e < 16; e++) {
            float4 h0 = *(const float4*)&inl[e][kc * 8];
            float4 h1 = *(const float4*)&inl[e][kc * 8 + 4];
            acc[e] = fmaf(h0.x, w[0], acc[e]); acc[e] = fmaf(h0.y, w[1], acc[e]);
            acc[e] = fmaf(h0.z, w[2], acc[e]); acc[e] = fmaf(h0.w, w[3], acc[e]);
            acc[e] = fmaf(h1.x, w[4], acc[e]); acc[e] = fmaf(h1.y, w[5], acc[e]);
            acc[e] = fmaf(h1.z, w[6], acc[e]); acc[e] = fmaf(h1.w, w[7], acc[e]);
        }
    }
    __syncthreads();
#pragma unroll
    for (int e = 0; e < 16; e++) inl[e][128 + j] = fmaxf(acc[e], 0.f);
    __syncthreads();
#pragma unroll
    for (int e = 0; e < 16; e++) acc[e] = b2[j];
    for (int kc = 0; kc < 16; kc++) {
        float w[8];
#pragma unroll
        for (int t = 0; t < 8; t++) w[t] = w2[(kc * 8 + t) * 128 + j];
#pragma unroll
        for (int e = 0; e < 16; e++) {
            float4 h0 = *(const float4*)&inl[e][128 + kc * 8];
            float4 h1 = *(const float4*)&inl[e][128 + kc * 8 + 4];
            acc[e] = fmaf(h0.x, w[0], acc[e]); acc[e] = fmaf(h0.y, w[1], acc[e]);
            acc[e] = fmaf(h0.z, w[2], acc[e]); acc[e] = fmaf(h0.w, w[3], acc[e]);
            acc[e] = fmaf(h1.x, w[4], acc[e]); acc[e] = fmaf(h1.y, w[5], acc[e]);
            acc[e] = fmaf(h1.z, w[6], acc[e]); acc[e] = fmaf(h1.w, w[7], acc[e]);
        }
    }
#pragma unroll
    for (int e = 0; e < 16; e++) {
        float v = inl[e][j] + acc[e];
        nl[(size_t)(base + e) * 128 + j] = v;
        nlb[(size_t)(base + e) * 128 + j] = f2bf(v);
    }
}

// ---------------- decoder: 128 -> 128 -> 3 ----------------

__global__ __launch_bounds__(128) void k_decode(
    const float* __restrict__ nl,
    const float* __restrict__ w1, const float* __restrict__ b1,
    const float* __restrict__ w2, const float* __restrict__ b2,
    float* __restrict__ out) {
    __shared__ float inl[16][128];
    __shared__ float hid[16][128];
    int j = threadIdx.x;
    int base = blockIdx.x * 16;
    for (int e = 0; e < 16; e++) inl[e][j] = nl[(size_t)(base + e) * 128 + j];
    __syncthreads();
    float acc[16];
#pragma unroll
    for (int e = 0; e < 16; e++) acc[e] = b1[j];
    for (int kc = 0; kc < 16; kc++) {
        float w[8];
#pragma unroll
        for (int t = 0; t < 8; t++) w[t] = w1[(kc * 8 + t) * 128 + j];
#pragma unroll
        for (int e = 0; e < 16; e++) {
            float4 h0 = *(const float4*)&inl[e][kc * 8];
            float4 h1 = *(const float4*)&inl[e][kc * 8 + 4];
            acc[e] = fmaf(h0.x, w[0], acc[e]); acc[e] = fmaf(h0.y, w[1], acc[e]);
            acc[e] = fmaf(h0.z, w[2], acc[e]); acc[e] = fmaf(h0.w, w[3], acc[e]);
            acc[e] = fmaf(h1.x, w[4], acc[e]); acc[e] = fmaf(h1.y, w[5], acc[e]);
            acc[e] = fmaf(h1.z, w[6], acc[e]); acc[e] = fmaf(h1.w, w[7], acc[e]);
        }
    }
#pragma unroll
    for (int e = 0; e < 16; e++) hid[e][j] = fmaxf(acc[e], 0.f);
    __syncthreads();
    if (j < 48) {
        int e = j / 3, ch = j - 3 * (j / 3);
        float s = b2[ch];
        for (int k = 0; k < 128; k++) s = fmaf(hid[e][k], w2[k * 3 + ch], s);
        out[(size_t)(base + e) * 3 + ch] = s;
    }
}

// ---------------- launch ----------------

extern "C" void kernel_launch(void* const* d_in, const int* in_sizes, int n_in,
                              void* d_out, int out_size, void* d_ws, size_t ws_size,
                              hipStream_t stream) {
    (void)in_sizes; (void)n_in; (void)out_size; (void)ws_size;
    const float* pos   = (const float*)d_in[0];
    const float* vel   = (const float*)d_in[1];
    const int*   rid   = (const int*)d_in[2];
    const int*   snd   = (const int*)d_in[3];
    const int*   rcv   = (const int*)d_in[4];
    const float* remb  = (const float*)d_in[5];
    const float* ne_w1 = (const float*)d_in[6];
    const float* ne_b1 = (const float*)d_in[7];
    const float* ne_w2 = (const float*)d_in[8];
    const float* ne_b2 = (const float*)d_in[9];
    const float* ee_w1 = (const float*)d_in[10];
    const float* ee_b1 = (const float*)d_in[11];
    const float* ee_w2 = (const float*)d_in[12];
    const float* ee_b2 = (const float*)d_in[13];
    const float* pe_w1 = (const float*)d_in[14];
    const float* pe_b1 = (const float*)d_in[15];
    const float* pe_w2 = (const float*)d_in[16];
    const float* pe_b2 = (const float*)d_in[17];
    const float* pn_w1 = (const float*)d_in[18];
    const float* pn_b1 = (const float*)d_in[19];
    const float* pn_w2 = (const float*)d_in[20];
    const float* pn_b2 = (const float*)d_in[21];
    const float* de_w1 = (const float*)d_in[22];
    const float* de_b1 = (const float*)d_in[23];
    const float* de_w2 = (const float*)d_in[24];
    const float* de_b2 = (const float*)d_in[25];
    float* out = (float*)d_out;

    // workspace carve (~248.5 MB)
    char* p = (char*)d_ws;
    auto carve = [&](size_t bytes) { void* q = (void*)p; p += (bytes + 15) & ~(size_t)15; return q; };
    unsigned short* el   = (unsigned short*)carve((size_t)NE * LDIM * 2);   // 204.8 MB
    float*          nl   = (float*)carve((size_t)NN * LDIM * 4);            // 25.6 MB
    unsigned short* nlb  = (unsigned short*)carve((size_t)NN * LDIM * 2);   // 12.8 MB
    unsigned short* w1f  = (unsigned short*)carve((size_t)NSTEPS * 12 * 8 * 64 * 8 * 2);
    unsigned short* w2f  = (unsigned short*)carve((size_t)NSTEPS * 4 * 8 * 64 * 8 * 2);
    int*            eidx = (int*)carve((size_t)NE * 4);                     // 3.2 MB
    int*            rs   = (int*)carve((size_t)(NN + 1) * 4);
    int*            cnt  = (int*)carve((size_t)NN * 4);
    int*            cur  = (int*)carve((size_t)NN * 4);
    float*          degf = (float*)carve((size_t)NN * 4);
    float*          csum = (float*)carve(16);

    hipMemsetAsync(cnt, 0, (size_t)NN * 4, stream);
    hipMemsetAsync(csum, 0, 16, stream);
    k_hist<<<NE / 256, 256, 0, stream>>>(rcv, cnt);
    k_scan<<<1, 1024, 0, stream>>>(cnt, rs, cur, degf);
    k_center<<<64, 256, 0, stream>>>(pos, csum);
    k_scatter<<<NE / 256, 256, 0, stream>>>(rcv, cur, eidx);
    k_prep_w<<<NSTEPS * 12 * 8, 64, 0, stream>>>(pe_w1, w1f, 12);
    k_prep_w<<<NSTEPS * 4 * 8, 64, 0, stream>>>(pe_w2, w2f, 4);
    k_node_enc<<<NN / 16, 128, 0, stream>>>(pos, vel, rid, remb, degf, csum,
                                            ne_w1, ne_b1, ne_w2, ne_b2, nl, nlb);
    k_edge_enc<<<NE / 32, 128, 0, stream>>>(pos, vel, rid, snd, rcv,
                                            ee_w1, ee_b1, ee_w2, ee_b2, (bf16*)el);
    for (int i = 0; i < NSTEPS; i++) {
        k_edge_step<<<NE / 128, 256, 0, stream>>>(el, nlb, snd, rcv,
            w1f + (size_t)i * 12 * 8 * 64 * 8, pe_b1 + i * 128,
            w2f + (size_t)i * 4 * 8 * 64 * 8, pe_b2 + i * 128);
        k_node_step<<<NN / 16, 128, 0, stream>>>(nl, nlb, el, eidx, rs,
            pn_w1 + (size_t)i * 256 * 128, pn_b1 + i * 128,
            pn_w2 + (size_t)i * 128 * 128, pn_b2 + i * 128);
    }
    k_decode<<<NN / 16, 128, 0, stream>>>(nl, de_w1, de_b1, de_w2, de_b2, out);
}